// Round 2
// baseline (488.508 us; speedup 1.0000x reference)
//
#include <hip/hip_runtime.h>
#include <math.h>

#define NCOL 64
#define M_ROWS 262144

__device__ __forceinline__ void cmac_conj(float2& acc, const float2 a, const float2 b) {
    // acc += conj(a) * b
    acc.x = fmaf(a.x, b.x, acc.x);
    acc.x = fmaf(a.y, b.y, acc.x);
    acc.y = fmaf(a.x, b.y, acc.y);
    acc.y = fmaf(-a.y, b.x, acc.y);
}
__device__ __forceinline__ void cmac(float2& acc, const float2 a, const float2 b) {
    // acc += a * b
    acc.x = fmaf(a.x, b.x, acc.x);
    acc.x = fmaf(-a.y, b.y, acc.x);
    acc.y = fmaf(a.x, b.y, acc.y);
    acc.y = fmaf(a.y, b.x, acc.y);
}

// ---------------- G = X^H X (nbuf replicated atomic partials) ----------------
#define GR_BLOCKS 2048
#define GR_ROWS (M_ROWS / GR_BLOCKS)   // 128
#define GR_TROWS 32

__global__ __launch_bounds__(256) void gram_kernel(const float4* __restrict__ X4,
                                                   float* __restrict__ Gbufs, int bufmask) {
    __shared__ float2 tile[GR_TROWS][66];  // pad 66: bank = (4r + 2c) mod 32
    const int t = threadIdx.x;
    const int j1 = t >> 4;   // 0..15; owns rows j1+{0,16,32,48} of G
    const int k1 = t & 15;   // 0..15; owns cols k1+{0,16,32,48}
    float2 acc[4][4];
#pragma unroll
    for (int a = 0; a < 4; ++a)
#pragma unroll
        for (int b = 0; b < 4; ++b) acc[a][b] = make_float2(0.f, 0.f);

    const int rbeg = blockIdx.x * GR_ROWS;
    for (int t0 = 0; t0 < GR_ROWS; t0 += GR_TROWS) {
        const float4* src = X4 + (size_t)(rbeg + t0) * (NCOL / 2);
#pragma unroll
        for (int i = 0; i < 4; ++i) {
            const int f = t + 256 * i;     // 1024 float4 = 32 rows x 32 float4
            const int row = f >> 5;
            const int c4 = f & 31;
            *reinterpret_cast<float4*>(&tile[row][c4 * 2]) = src[f];
        }
        __syncthreads();
#pragma unroll 2
        for (int r = 0; r < GR_TROWS; ++r) {
            float2 xa[4], xb[4];
#pragma unroll
            for (int a = 0; a < 4; ++a) xa[a] = tile[r][j1 + 16 * a];
#pragma unroll
            for (int b = 0; b < 4; ++b) xb[b] = tile[r][k1 + 16 * b];
#pragma unroll
            for (int a = 0; a < 4; ++a)
#pragma unroll
                for (int b = 0; b < 4; ++b) cmac_conj(acc[a][b], xa[a], xb[b]);
        }
        __syncthreads();
    }
    float* G = Gbufs + (size_t)(blockIdx.x & bufmask) * 8192;
#pragma unroll
    for (int a = 0; a < 4; ++a)
#pragma unroll
        for (int b = 0; b < 4; ++b) {
            const int idx = (j1 + 16 * a) * NCOL + (k1 + 16 * b);
            atomicAdd(&G[2 * idx], acc[a][b].x);
            atomicAdd(&G[2 * idx + 1], acc[a][b].y);
        }
}

// ---------------- reduce bufs, Cholesky (upper R), in-place R^{-1} ----------------
__global__ __launch_bounds__(256) void cholinv_kernel(const float* __restrict__ Gbufs, int nbuf,
                                                      float2* __restrict__ RinvOut) {
    __shared__ float2 A[64][64];
    __shared__ float2 rowbuf[64];
    __shared__ float dinv[64];
    const int t = threadIdx.x;
    float* A1 = reinterpret_cast<float*>(&A[0][0]);
    for (int idx = t; idx < 8192; idx += 256) {
        float s = 0.f;
        for (int b = 0; b < nbuf; ++b) s += Gbufs[(size_t)b * 8192 + idx];
        A1[idx] = s;
    }
    __syncthreads();

    // right-looking complex Cholesky, upper triangular R in-place
    for (int i = 0; i < 64; ++i) {
        if (t == 0) {
            const float d = sqrtf(fmaxf(A[i][i].x, 1e-30f));
            dinv[i] = 1.0f / d;
            A[i][i] = make_float2(d, 0.f);
        }
        __syncthreads();
        const float di = dinv[i];
        for (int k = i + 1 + t; k < 64; k += 256) {
            A[i][k].x *= di;
            A[i][k].y *= di;
        }
        __syncthreads();
        const int n = 63 - i;
        for (int idx = t; idx < n * n; idx += 256) {
            const int j = i + 1 + idx / n;
            const int k = i + 1 + idx % n;
            if (k >= j) {
                const float2 rij = A[i][j];
                const float2 rik = A[i][k];
                float2 v = A[j][k];
                v.x -= rij.x * rik.x + rij.y * rik.y;
                v.y -= rij.x * rik.y - rij.y * rik.x;
                A[j][k] = v;
            }
        }
        __syncthreads();
    }

    // in-place upper-triangular inversion: upper(A) := R^{-1}
    if (t < 64) A[t][t] = make_float2(dinv[t], 0.f);
    __syncthreads();
    for (int i = 62; i >= 0; --i) {
        if (t < 64 && t > i) rowbuf[t] = A[i][t];
        __syncthreads();
        if (t < 64 && t > i) {
            const int k = t;
            float2 s = make_float2(0.f, 0.f);
            for (int j = i + 1; j <= k; ++j) cmac(s, rowbuf[j], A[j][k]);
            A[i][k] = make_float2(-s.x * dinv[i], -s.y * dinv[i]);
        }
        __syncthreads();
    }
    for (int i = t; i < 4096; i += 256) {
        const int r = i >> 6, c = i & 63;
        RinvOut[i] = (c >= r) ? A[r][c] : make_float2(0.f, 0.f);
    }
}

// ---------------- Q = X * Rinv (triangular j-loop) ----------------
#define AP_BLOCKS 2048
#define AP_ROWS (M_ROWS / AP_BLOCKS)   // 128
#define AP_TROWS 32

__global__ __launch_bounds__(256) void apply_kernel(const float4* __restrict__ X4,
                                                    const float4* __restrict__ Rinv4,
                                                    float2* __restrict__ Q2) {
    __shared__ float2 W[64][64];          // Rinv row-major; bank = 2k mod 32 (k per-lane -> free)
    __shared__ float2 tile[AP_TROWS][66]; // pad 66
    const int t = threadIdx.x;
#pragma unroll
    for (int i = 0; i < 8; ++i) {
        const int f = t + 256 * i;        // 2048 float4
        reinterpret_cast<float4*>(&W[0][0])[f] = Rinv4[f];
    }
    const int k1 = t & 15;    // cols k1+{0,16,32,48}
    const int r1 = t >> 4;    // rows r1, r1+16
    const int rbeg = blockIdx.x * AP_ROWS;
    for (int t0 = 0; t0 < AP_ROWS; t0 += AP_TROWS) {
        const float4* src = X4 + (size_t)(rbeg + t0) * (NCOL / 2);
#pragma unroll
        for (int i = 0; i < 4; ++i) {
            const int f = t + 256 * i;    // 1024 float4 = 32 rows x 32
            const int row = f >> 5;
            const int c4 = f & 31;
            *reinterpret_cast<float4*>(&tile[row][c4 * 2]) = src[f];
        }
        __syncthreads();
        float2 acc[2][4];
#pragma unroll
        for (int a = 0; a < 2; ++a)
#pragma unroll
            for (int b = 0; b < 4; ++b) acc[a][b] = make_float2(0.f, 0.f);

        // Rinv upper-triangular: for j-segment s, only col-groups b>=s can have k>=j.
        // Skipped terms multiply exact zeros (lower triangle zeroed) -> bit-identical.
#define SEG(JLO, JHI, BMIN)                                          \
        _Pragma("unroll 2")                                          \
        for (int j = (JLO); j < (JHI); ++j) {                        \
            const float2 x0 = tile[r1][j];                           \
            const float2 x1 = tile[r1 + 16][j];                      \
            _Pragma("unroll")                                        \
            for (int b = (BMIN); b < 4; ++b) {                       \
                const float2 w = W[j][k1 + 16 * b];                  \
                cmac(acc[0][b], x0, w);                              \
                cmac(acc[1][b], x1, w);                              \
            }                                                        \
        }
        SEG(0, 16, 0)
        SEG(16, 32, 1)
        SEG(32, 48, 2)
        SEG(48, 64, 3)
#undef SEG

#pragma unroll
        for (int a = 0; a < 2; ++a) {
            const size_t row = (size_t)(rbeg + t0 + r1 + 16 * a);
#pragma unroll
            for (int b = 0; b < 4; ++b) Q2[row * NCOL + k1 + 16 * b] = acc[a][b];
        }
        __syncthreads();
    }
}

extern "C" void kernel_launch(void* const* d_in, const int* in_sizes, int n_in,
                              void* d_out, int out_size, void* d_ws, size_t ws_size,
                              hipStream_t stream) {
    (void)in_sizes; (void)n_in; (void)out_size;
    const float4* X4 = reinterpret_cast<const float4*>(d_in[0]);
    float* Gbufs = reinterpret_cast<float*>(d_ws);
    int nbuf = 1;  // replicated G partial buffers, sized to available ws
    while (nbuf < 16 && (size_t)(2 * nbuf) * 32768 + 32768 <= ws_size) nbuf <<= 1;
    float2* Rinv = reinterpret_cast<float2*>((char*)d_ws + (size_t)nbuf * 32768);

    hipMemsetAsync(Gbufs, 0, (size_t)nbuf * 32768, stream);
    gram_kernel<<<GR_BLOCKS, 256, 0, stream>>>(X4, Gbufs, nbuf - 1);
    cholinv_kernel<<<1, 256, 0, stream>>>(Gbufs, nbuf, Rinv);
    apply_kernel<<<AP_BLOCKS, 256, 0, stream>>>(X4, reinterpret_cast<const float4*>(Rinv),
                                                reinterpret_cast<float2*>(d_out));
}

// Round 3
// 424.716 us; speedup vs baseline: 1.1502x; 1.1502x over previous
//
#include <hip/hip_runtime.h>
#include <math.h>

#define NCOL 64
#define M_ROWS 262144

__device__ __forceinline__ void cmac_conj(float2& acc, const float2 a, const float2 b) {
    // acc += conj(a) * b
    acc.x = fmaf(a.x, b.x, acc.x);
    acc.x = fmaf(a.y, b.y, acc.x);
    acc.y = fmaf(a.x, b.y, acc.y);
    acc.y = fmaf(-a.y, b.x, acc.y);
}
__device__ __forceinline__ void cmac(float2& acc, const float2 a, const float2 b) {
    // acc += a * b
    acc.x = fmaf(a.x, b.x, acc.x);
    acc.x = fmaf(-a.y, b.y, acc.x);
    acc.y = fmaf(a.x, b.y, acc.y);
    acc.y = fmaf(a.y, b.x, acc.y);
}
__device__ __forceinline__ float lane_bcast(float v, int lane) {
    return __uint_as_float(__builtin_amdgcn_readlane(__float_as_uint(v), lane));
}

// ---------------- G = X^H X, upper-triangle groups only ----------------
#define GR_BLOCKS 2048
#define GR_ROWS (M_ROWS / GR_BLOCKS)   // 128
#define GR_TROWS 32

__global__ __launch_bounds__(256) void gram_kernel(const float4* __restrict__ X4,
                                                   float* __restrict__ Gbufs, int bufmask) {
    __shared__ float2 tile[GR_TROWS][66];
    const int t = threadIdx.x;
    const int j1 = t >> 4;   // G rows j1+{0,16,32,48}
    const int k1 = t & 15;   // G cols k1+{0,16,32,48}
    float2 acc[4][4];
#pragma unroll
    for (int a = 0; a < 4; ++a)
#pragma unroll
        for (int b = 0; b < 4; ++b) acc[a][b] = make_float2(0.f, 0.f);

    const int rbeg = blockIdx.x * GR_ROWS;
    for (int t0 = 0; t0 < GR_ROWS; t0 += GR_TROWS) {
        const float4* src = X4 + (size_t)(rbeg + t0) * (NCOL / 2);
#pragma unroll
        for (int i = 0; i < 4; ++i) {
            const int f = t + 256 * i;     // 1024 float4 = 32 rows x 32 float4
            const int row = f >> 5;
            const int c4 = f & 31;
            *reinterpret_cast<float4*>(&tile[row][c4 * 2]) = src[f];
        }
        __syncthreads();
#pragma unroll 2
        for (int r = 0; r < GR_TROWS; ++r) {
            float2 xa[4], xb[4];
#pragma unroll
            for (int a = 0; a < 4; ++a) xa[a] = tile[r][j1 + 16 * a];
#pragma unroll
            for (int b = 0; b < 4; ++b) xb[b] = tile[r][k1 + 16 * b];
            // Cholesky only reads the upper triangle of G: skip groups a > b.
#pragma unroll
            for (int a = 0; a < 4; ++a)
#pragma unroll
                for (int b = 0; b < 4; ++b)
                    if (a <= b) cmac_conj(acc[a][b], xa[a], xb[b]);
        }
        __syncthreads();
    }
    float* G = Gbufs + (size_t)(blockIdx.x & bufmask) * 8192;
#pragma unroll
    for (int a = 0; a < 4; ++a)
#pragma unroll
        for (int b = 0; b < 4; ++b)
            if (a <= b) {
                const int idx = (j1 + 16 * a) * NCOL + (k1 + 16 * b);
                atomicAdd(&G[2 * idx], acc[a][b].x);
                atomicAdd(&G[2 * idx + 1], acc[a][b].y);
            }
}

// ---------------- single-wave: reduce + Cholesky + triangular inverse ----------------
__global__ __launch_bounds__(64) void cholinv_kernel(const float* __restrict__ Gbufs, int nbuf,
                                                     float2* __restrict__ RinvOut) {
    __shared__ float2 R[64 * 64];   // row-major; after phase 3, row i = R[i][:], diag = {d, dinv}
    const int k = threadIdx.x;      // lane = column

    // 1) reduce partial G buffers into LDS
    {
        float4* R4 = reinterpret_cast<float4*>(R);
        const float4* Gb4 = reinterpret_cast<const float4*>(Gbufs);
        for (int it = 0; it < 32; ++it) {
            const int f = k + 64 * it;      // 2048 float4
            float4 s = Gb4[f];
            for (int b = 1; b < nbuf; ++b) {
                const float4 u = Gb4[b * 2048 + f];
                s.x += u.x; s.y += u.y; s.z += u.z; s.w += u.w;
            }
            R4[f] = s;
        }
    }
    __syncthreads();

    // 2) lane k <- column k of G (lower-triangle entries unused/garbage-tolerant)
    float2 a[64];
#pragma unroll
    for (int j = 0; j < 64; ++j) a[j] = R[j * 64 + k];

    // 3) Cholesky, fully unrolled, zero barriers. Row i of R -> LDS.
#pragma unroll
    for (int i = 0; i < 64; ++i) {
        const float dsq = lane_bcast(a[i].x, i);
        const float d = sqrtf(fmaxf(dsq, 1e-30f));
        const float dinv = 1.0f / d;
        float2 rr;                       // R[i][k] in lane k (valid for k >= i)
        rr.x = a[i].x * dinv;
        rr.y = a[i].y * dinv;
        if (k == i) { rr.x = d; rr.y = 0.f; }
        float2 st = rr;
        if (k == i) st.y = dinv;         // pack dinv into diag imag slot
        R[i * 64 + k] = st;
#pragma unroll
        for (int j = i + 1; j < 64; ++j) {
            const float rijx = lane_bcast(rr.x, j);
            const float rijy = lane_bcast(rr.y, j);
            // a[j] -= conj(rij) * rr
            a[j].x = fmaf(-rijx, rr.x, fmaf(-rijy, rr.y, a[j].x));
            a[j].y = fmaf(-rijx, rr.y, fmaf( rijy, rr.x, a[j].y));
        }
    }
    __syncthreads();

    // 4) lane k <- column k of Rinv (reuse a[]); self-masking recurrence:
    //    a[j] = W[j][k], zero for j > k, so lower triangle stays exactly 0.
    const float dk = R[k * 64 + k].y;
#pragma unroll
    for (int j = 0; j < 64; ++j)
        a[j] = (j == k) ? make_float2(dk, 0.f) : make_float2(0.f, 0.f);
#pragma unroll
    for (int ii = 0; ii < 63; ++ii) {
        const int i = 62 - ii;
        float2 s = make_float2(0.f, 0.f);
#pragma unroll
        for (int j = i + 1; j < 64; ++j) {
            const float2 rij = R[i * 64 + j];   // uniform broadcast read
            s.x = fmaf(rij.x, a[j].x, fmaf(-rij.y, a[j].y, s.x));
            s.y = fmaf(rij.x, a[j].y, fmaf( rij.y, a[j].x, s.y));
        }
        const float di = R[i * 64 + i].y;       // dinv_i
        if (k != i) { a[i].x = -di * s.x; a[i].y = -di * s.y; }
    }

    // 5) write Rinv (exact zeros below diagonal)
#pragma unroll
    for (int i = 0; i < 64; ++i) RinvOut[i * 64 + k] = a[i];
}

// ---------------- Q = X * Rinv (triangular j-loop) ----------------
#define AP_BLOCKS 2048
#define AP_ROWS (M_ROWS / AP_BLOCKS)   // 128
#define AP_TROWS 32

__global__ __launch_bounds__(256) void apply_kernel(const float4* __restrict__ X4,
                                                    const float4* __restrict__ Rinv4,
                                                    float2* __restrict__ Q2) {
    __shared__ float2 W[64][64];
    __shared__ float2 tile[AP_TROWS][66];
    const int t = threadIdx.x;
#pragma unroll
    for (int i = 0; i < 8; ++i) {
        const int f = t + 256 * i;
        reinterpret_cast<float4*>(&W[0][0])[f] = Rinv4[f];
    }
    const int k1 = t & 15;
    const int r1 = t >> 4;
    const int rbeg = blockIdx.x * AP_ROWS;
    for (int t0 = 0; t0 < AP_ROWS; t0 += AP_TROWS) {
        const float4* src = X4 + (size_t)(rbeg + t0) * (NCOL / 2);
#pragma unroll
        for (int i = 0; i < 4; ++i) {
            const int f = t + 256 * i;
            const int row = f >> 5;
            const int c4 = f & 31;
            *reinterpret_cast<float4*>(&tile[row][c4 * 2]) = src[f];
        }
        __syncthreads();
        float2 acc[2][4];
#pragma unroll
        for (int a = 0; a < 2; ++a)
#pragma unroll
            for (int b = 0; b < 4; ++b) acc[a][b] = make_float2(0.f, 0.f);

#define SEG(JLO, JHI, BMIN)                                          \
        _Pragma("unroll 2")                                          \
        for (int j = (JLO); j < (JHI); ++j) {                        \
            const float2 x0 = tile[r1][j];                           \
            const float2 x1 = tile[r1 + 16][j];                      \
            _Pragma("unroll")                                        \
            for (int b = (BMIN); b < 4; ++b) {                       \
                const float2 w = W[j][k1 + 16 * b];                  \
                cmac(acc[0][b], x0, w);                              \
                cmac(acc[1][b], x1, w);                              \
            }                                                        \
        }
        SEG(0, 16, 0)
        SEG(16, 32, 1)
        SEG(32, 48, 2)
        SEG(48, 64, 3)
#undef SEG

#pragma unroll
        for (int a = 0; a < 2; ++a) {
            const size_t row = (size_t)(rbeg + t0 + r1 + 16 * a);
#pragma unroll
            for (int b = 0; b < 4; ++b) Q2[row * NCOL + k1 + 16 * b] = acc[a][b];
        }
        __syncthreads();
    }
}

extern "C" void kernel_launch(void* const* d_in, const int* in_sizes, int n_in,
                              void* d_out, int out_size, void* d_ws, size_t ws_size,
                              hipStream_t stream) {
    (void)in_sizes; (void)n_in; (void)out_size;
    const float4* X4 = reinterpret_cast<const float4*>(d_in[0]);
    float* Gbufs = reinterpret_cast<float*>(d_ws);
    int nbuf = 1;
    while (nbuf < 16 && (size_t)(2 * nbuf) * 32768 + 32768 <= ws_size) nbuf <<= 1;
    float2* Rinv = reinterpret_cast<float2*>((char*)d_ws + (size_t)nbuf * 32768);

    hipMemsetAsync(Gbufs, 0, (size_t)nbuf * 32768, stream);
    gram_kernel<<<GR_BLOCKS, 256, 0, stream>>>(X4, Gbufs, nbuf - 1);
    cholinv_kernel<<<1, 64, 0, stream>>>(Gbufs, nbuf, Rinv);
    apply_kernel<<<AP_BLOCKS, 256, 0, stream>>>(X4, reinterpret_cast<const float4*>(Rinv),
                                                reinterpret_cast<float2*>(d_out));
}